// Round 2
// baseline (738.828 us; speedup 1.0000x reference)
//
#include <hip/hip_runtime.h>
#include <math.h>

#define NROWS 131072
#define NSEG  64
#define HH    512
#define LDK   40   // padded LDS row for fallback kernel

typedef unsigned short u16;
typedef unsigned int   u32;
typedef __attribute__((ext_vector_type(8))) short short8;
typedef __attribute__((ext_vector_type(8))) u16   us8;
typedef __attribute__((ext_vector_type(4))) float f32x4;

__device__ __forceinline__ u32 f2u(float f){ union {float f; u32 u;} c; c.f=f; return c.u; }
__device__ __forceinline__ float u2f(u32 u){ union {u32 u; float f;} c; c.u=u; return c.f; }
__device__ __forceinline__ u16 bf16_rne(float f){
  u32 u = f2u(f);
  u32 r = u + 0x7FFFu + ((u >> 16) & 1u);
  return (u16)(r >> 16);
}
__device__ __forceinline__ float fast_tanh(float x){
  float e = __expf(2.0f * x);
  return 1.0f - __fdividef(2.0f, e + 1.0f);
}
// async 16B global->LDS; LDS dest is wave-uniform base + lane*16
__device__ __forceinline__ void gload_lds16(const void* g, void* l) {
  __builtin_amdgcn_global_load_lds((const __attribute__((address_space(1))) void*)g,
                                   (__attribute__((address_space(3))) void*)l, 16, 0, 0);
}

// ---------------- pre-pass: enc fp32 -> bf16 hi (trunc) / lo (rne of residual)
__global__ __launch_bounds__(256)
void enc_split_kernel(const float* __restrict__ enc, u16* __restrict__ hi, u16* __restrict__ lo)
{
  const size_t i0 = ((size_t)blockIdx.x * 256 + threadIdx.x) * 8;
  float4 a = *(const float4*)(enc + i0);
  float4 b = *(const float4*)(enc + i0 + 4);
  float x[8] = {a.x, a.y, a.z, a.w, b.x, b.y, b.z, b.w};
  u16 h[8], l[8];
  #pragma unroll
  for (int i = 0; i < 8; i++) {
    const u32 u = f2u(x[i]);
    h[i] = (u16)(u >> 16);
    l[i] = bf16_rne(x[i] - u2f(u & 0xFFFF0000u));
  }
  *(us8*)(hi + i0) = *(const us8*)h;
  *(us8*)(lo + i0) = *(const us8*)l;
}

// ---------------- hproj[b][j] = sum_k hidden[b][k] * W[j][k]  (coalesced, reg-resident hidden)
__global__ __launch_bounds__(256)
void hproj_kernel(const float* __restrict__ hidden, const float* __restrict__ W,
                  float* __restrict__ hproj)
{
  const int b    = blockIdx.x;
  const int tid  = threadIdx.x;
  const int wave = tid >> 6;
  const int lane = tid & 63;
  const float* hrow = hidden + (size_t)b * HH + lane * 8;
  const float4 h0 = *(const float4*)(hrow);
  const float4 h1 = *(const float4*)(hrow + 4);
  for (int j = wave; j < HH; j += 4) {
    const float* wrow = W + (size_t)j * 1024 + lane * 8;
    const float4 w0 = *(const float4*)(wrow);
    const float4 w1 = *(const float4*)(wrow + 4);
    float acc = h0.x*w0.x + h0.y*w0.y + h0.z*w0.z + h0.w*w0.w
              + h1.x*w1.x + h1.y*w1.y + h1.z*w1.z + h1.w*w1.w;
    #pragma unroll
    for (int o = 32; o; o >>= 1) acc += __shfl_xor(acc, o);
    if (lane == 0) hproj[(size_t)b * HH + j] = acc;
  }
}

// ---------------- split W2 = W[:, 512:1024] into bf16 hi/lo, row-major [j][k]
__global__ __launch_bounds__(256)
void w2split_kernel(const float* __restrict__ W, u16* __restrict__ hi, u16* __restrict__ lo)
{
  const int idx = blockIdx.x * 256 + threadIdx.x;   // j*512 + k
  const int j = idx >> 9, k = idx & 511;
  const float x = W[(size_t)j * 1024 + 512 + k];
  const u32 u = f2u(x);
  hi[idx] = (u16)(u >> 16);
  lo[idx] = bf16_rne(x - u2f(u & 0xFFFF0000u));
}

// ---------------- main GEMM (fast path): pure-bf16 staging via global_load_lds
__global__ __launch_bounds__(256, 3)
void gemm_fast_kernel(const u16* __restrict__ eh, const u16* __restrict__ el,
                      const u16* __restrict__ w2hi, const u16* __restrict__ w2lo,
                      const float* __restrict__ hproj, const float* __restrict__ vvec,
                      const int* __restrict__ seg, float* __restrict__ scores)
{
  __shared__ u16 sAh[128 * 32];
  __shared__ u16 sAl[128 * 32];
  __shared__ u16 sBh[128 * 32];
  __shared__ u16 sBl[128 * 32];

  const int tid  = threadIdx.x;
  const int bx   = blockIdx.x;
  const int row0 = (bx >> 2) * 128;   // col-tile fastest: A re-reads land in L3
  const int col0 = (bx & 3) * 128;

  const int wave = tid >> 6;
  const int lane = tid & 63;
  const int wr   = (wave >> 1) * 64;
  const int wc   = (wave & 1) * 64;
  const int l15  = lane & 15;
  const int quad = lane >> 4;

  // staging map: slot s = i*256 + tid  ->  row = i*64 + (tid>>2), chunk = tid&3
  const int rr    = tid >> 2;
  const int coff  = (tid & 3) * 8;
  const int wbase = (tid >> 6) * 512;   // wave-uniform LDS u16 base (slot*8)

  const u16* gAh = eh   + (size_t)(row0 + rr) * HH + coff;
  const u16* gAl = el   + (size_t)(row0 + rr) * HH + coff;
  const u16* gBh = w2hi + (size_t)(col0 + rr) * HH + coff;
  const u16* gBl = w2lo + (size_t)(col0 + rr) * HH + coff;

  f32x4 acc[4][4];
  #pragma unroll
  for (int i = 0; i < 4; i++)
    #pragma unroll
    for (int j = 0; j < 4; j++)
      acc[i][j] = (f32x4){0.f, 0.f, 0.f, 0.f};

  for (int ks = 0; ks < HH; ks += 32) {
    gload_lds16(gAh + ks,            &sAh[wbase]);
    gload_lds16(gAh + ks + 64 * HH,  &sAh[2048 + wbase]);
    gload_lds16(gAl + ks,            &sAl[wbase]);
    gload_lds16(gAl + ks + 64 * HH,  &sAl[2048 + wbase]);
    gload_lds16(gBh + ks,            &sBh[wbase]);
    gload_lds16(gBh + ks + 64 * HH,  &sBh[2048 + wbase]);
    gload_lds16(gBl + ks,            &sBl[wbase]);
    gload_lds16(gBl + ks + 64 * HH,  &sBl[2048 + wbase]);
    __syncthreads();

    short8 bhf[4], blf[4];
    #pragma unroll
    for (int j = 0; j < 4; j++) {
      const int br = (wc + j * 16 + l15) * 32 + quad * 8;
      bhf[j] = *(const short8*)&sBh[br];
      blf[j] = *(const short8*)&sBl[br];
    }
    #pragma unroll
    for (int i = 0; i < 4; i++) {
      const int ar = (wr + i * 16 + l15) * 32 + quad * 8;
      const short8 ah = *(const short8*)&sAh[ar];
      const short8 al = *(const short8*)&sAl[ar];
      #pragma unroll
      for (int j = 0; j < 4; j++) {
        acc[i][j] = __builtin_amdgcn_mfma_f32_16x16x32_bf16(ah, bhf[j], acc[i][j], 0, 0, 0);
        acc[i][j] = __builtin_amdgcn_mfma_f32_16x16x32_bf16(al, bhf[j], acc[i][j], 0, 0, 0);
        acc[i][j] = __builtin_amdgcn_mfma_f32_16x16x32_bf16(ah, blf[j], acc[i][j], 0, 0, 0);
      }
    }
    __syncthreads();
  }

  int   jn[4];
  float vv[4];
  #pragma unroll
  for (int j = 0; j < 4; j++) { jn[j] = col0 + wc + j * 16 + l15; vv[j] = vvec[jn[j]]; }

  #pragma unroll
  for (int i = 0; i < 4; i++) {
    #pragma unroll
    for (int r = 0; r < 4; r++) {
      const int gn = row0 + wr + i * 16 + quad * 4 + r;    // C/D: row=(lane>>4)*4+reg
      const float* hp = hproj + (size_t)seg[gn] * HH;
      float p = 0.f;
      #pragma unroll
      for (int j = 0; j < 4; j++) {
        const float c = acc[i][j][r] + hp[jn[j]];
        p += fast_tanh(c) * vv[j];
      }
      p += __shfl_xor(p, 1);
      p += __shfl_xor(p, 2);
      p += __shfl_xor(p, 4);
      p += __shfl_xor(p, 8);
      if (l15 == 0) atomicAdd(&scores[gn], p);
    }
  }
}

// ---------------- fallback GEMM (in-kernel conversion; used only if ws too small)
__global__ __launch_bounds__(256, 3)
void gemm_score_kernel(const float* __restrict__ enc,
                       const u16* __restrict__ w2hi,
                       const u16* __restrict__ w2lo,
                       const float* __restrict__ hproj,
                       const float* __restrict__ vvec,
                       const int* __restrict__ seg,
                       float* __restrict__ scores)
{
  __shared__ u16 sAhi[128 * LDK];
  __shared__ u16 sAlo[128 * LDK];
  __shared__ u16 sBhi[128 * LDK];
  __shared__ u16 sBlo[128 * LDK];

  const int tid  = threadIdx.x;
  const int bx   = blockIdx.x;
  const int row0 = (bx >> 2) * 128;
  const int col0 = (bx & 3) * 128;

  const int wave = tid >> 6;
  const int lane = tid & 63;
  const int wr   = (wave >> 1) * 64;
  const int wc   = (wave & 1) * 64;
  const int l15  = lane & 15;
  const int quad = lane >> 4;

  const int sr = tid >> 1;
  const int sk = (tid & 1) * 16;

  f32x4 acc[4][4];
  #pragma unroll
  for (int i = 0; i < 4; i++)
    #pragma unroll
    for (int j = 0; j < 4; j++)
      acc[i][j] = (f32x4){0.f, 0.f, 0.f, 0.f};

  const float* gA  = enc  + (size_t)(row0 + sr) * HH + sk;
  const u16*   gBh = w2hi + (size_t)(col0 + sr) * HH + sk;
  const u16*   gBl = w2lo + (size_t)(col0 + sr) * HH + sk;
  u16* wAhi = &sAhi[sr * LDK + sk];
  u16* wAlo = &sAlo[sr * LDK + sk];
  u16* wBhi = &sBhi[sr * LDK + sk];
  u16* wBlo = &sBlo[sr * LDK + sk];

  for (int ks = 0; ks < HH; ks += 32) {
    float xb[16];
    *(float4*)(&xb[0])  = *(const float4*)(gA + ks + 0);
    *(float4*)(&xb[4])  = *(const float4*)(gA + ks + 4);
    *(float4*)(&xb[8])  = *(const float4*)(gA + ks + 8);
    *(float4*)(&xb[12]) = *(const float4*)(gA + ks + 12);
    u16 hb[16], lb[16];
    #pragma unroll
    for (int i = 0; i < 16; i++) {
      const u32 u = f2u(xb[i]);
      hb[i] = (u16)(u >> 16);
      lb[i] = bf16_rne(xb[i] - u2f(u & 0xFFFF0000u));
    }
    *(us8*)(wAhi)     = *(const us8*)&hb[0];
    *(us8*)(wAhi + 8) = *(const us8*)&hb[8];
    *(us8*)(wAlo)     = *(const us8*)&lb[0];
    *(us8*)(wAlo + 8) = *(const us8*)&lb[8];
    *(us8*)(wBhi)     = *(const us8*)(gBh + ks);
    *(us8*)(wBhi + 8) = *(const us8*)(gBh + ks + 8);
    *(us8*)(wBlo)     = *(const us8*)(gBl + ks);
    *(us8*)(wBlo + 8) = *(const us8*)(gBl + ks + 8);
    __syncthreads();

    short8 bhf[4], blf[4];
    #pragma unroll
    for (int j = 0; j < 4; j++) {
      const int br = (wc + j * 16 + l15) * LDK + quad * 8;
      bhf[j] = *(const short8*)&sBhi[br];
      blf[j] = *(const short8*)&sBlo[br];
    }
    #pragma unroll
    for (int i = 0; i < 4; i++) {
      const int ar = (wr + i * 16 + l15) * LDK + quad * 8;
      const short8 ah = *(const short8*)&sAhi[ar];
      const short8 al = *(const short8*)&sAlo[ar];
      #pragma unroll
      for (int j = 0; j < 4; j++) {
        acc[i][j] = __builtin_amdgcn_mfma_f32_16x16x32_bf16(ah, bhf[j], acc[i][j], 0, 0, 0);
        acc[i][j] = __builtin_amdgcn_mfma_f32_16x16x32_bf16(al, bhf[j], acc[i][j], 0, 0, 0);
        acc[i][j] = __builtin_amdgcn_mfma_f32_16x16x32_bf16(ah, blf[j], acc[i][j], 0, 0, 0);
      }
    }
    __syncthreads();
  }

  int   jn[4];
  float vv[4];
  #pragma unroll
  for (int j = 0; j < 4; j++) { jn[j] = col0 + wc + j * 16 + l15; vv[j] = vvec[jn[j]]; }

  #pragma unroll
  for (int i = 0; i < 4; i++) {
    #pragma unroll
    for (int r = 0; r < 4; r++) {
      const int gn = row0 + wr + i * 16 + quad * 4 + r;
      const float* hp = hproj + (size_t)seg[gn] * HH;
      float p = 0.f;
      #pragma unroll
      for (int j = 0; j < 4; j++) {
        const float c = acc[i][j][r] + hp[jn[j]];
        p += fast_tanh(c) * vv[j];
      }
      p += __shfl_xor(p, 1);
      p += __shfl_xor(p, 2);
      p += __shfl_xor(p, 4);
      p += __shfl_xor(p, 8);
      if (l15 == 0) atomicAdd(&scores[gn], p);
    }
  }
}

// ---------------- segment softmax: one block per segment (ids sorted)
__global__ __launch_bounds__(256)
void seg_softmax_kernel(const float* __restrict__ scores, const int* __restrict__ seg,
                        float* __restrict__ out)
{
  const int b    = blockIdx.x;
  const int tid  = threadIdx.x;
  const int wv   = tid >> 6;
  const int lane = tid & 63;
  __shared__ float red[4];

  int lo = 0, hi = NROWS;
  while (lo < hi) { int mid = (lo + hi) >> 1; if (seg[mid] < b) lo = mid + 1; else hi = mid; }
  const int start = lo;
  lo = 0; hi = NROWS;
  while (lo < hi) { int mid = (lo + hi) >> 1; if (seg[mid] < b + 1) lo = mid + 1; else hi = mid; }
  const int end = lo;

  float lm = -3.4e38f;
  for (int i = start + tid; i < end; i += 256) lm = fmaxf(lm, scores[i]);
  #pragma unroll
  for (int o = 32; o; o >>= 1) lm = fmaxf(lm, __shfl_xor(lm, o));
  if (lane == 0) red[wv] = lm;
  __syncthreads();
  const float gm = fmaxf(fmaxf(red[0], red[1]), fmaxf(red[2], red[3]));
  __syncthreads();

  float ls = 0.f;
  for (int i = start + tid; i < end; i += 256) ls += expf(scores[i] - gm);
  #pragma unroll
  for (int o = 32; o; o >>= 1) ls += __shfl_xor(ls, o);
  if (lane == 0) red[wv] = ls;
  __syncthreads();
  const float denom = red[0] + red[1] + red[2] + red[3];
  const float inv = 1.0f / denom;

  for (int i = start + tid; i < end; i += 256) out[i] = expf(scores[i] - gm) * inv;
}

extern "C" void kernel_launch(void* const* d_in, const int* in_sizes, int n_in,
                              void* d_out, int out_size, void* d_ws, size_t ws_size,
                              hipStream_t stream)
{
  const float* hidden = (const float*)d_in[0];
  const float* enc    = (const float*)d_in[1];
  const int*   seg    = (const int*)d_in[2];
  const float* W      = (const float*)d_in[3];
  const float* vvec   = (const float*)d_in[4];
  float* out = (float*)d_out;

  // ws layout: scores | hproj | w2hi | w2lo | encHi | encLo
  float* scores = (float*)d_ws;
  float* hproj  = scores + NROWS;
  u16*   w2hi   = (u16*)(hproj + NSEG * HH);
  u16*   w2lo   = w2hi + (size_t)HH * HH;
  u16*   encHi  = w2lo + (size_t)HH * HH;
  u16*   encLo  = encHi + (size_t)NROWS * HH;

  const size_t need_big = (size_t)NROWS * 4 + (size_t)NSEG * HH * 4
                        + (size_t)HH * HH * 2 * 2 + (size_t)NROWS * HH * 2 * 2;

  hipMemsetAsync(scores, 0, NROWS * sizeof(float), stream);
  hproj_kernel<<<NSEG, 256, 0, stream>>>(hidden, W, hproj);
  w2split_kernel<<<(HH * HH) / 256, 256, 0, stream>>>(W, w2hi, w2lo);

  if (ws_size >= need_big) {
    enc_split_kernel<<<(NROWS * HH) / (256 * 8), 256, 0, stream>>>(enc, encHi, encLo);
    gemm_fast_kernel<<<(NROWS / 128) * 4, 256, 0, stream>>>(encHi, encLo, w2hi, w2lo,
                                                            hproj, vvec, seg, scores);
  } else {
    gemm_score_kernel<<<(NROWS / 128) * 4, 256, 0, stream>>>(enc, w2hi, w2lo,
                                                             hproj, vvec, seg, scores);
  }
  seg_softmax_kernel<<<NSEG, 256, 0, stream>>>(scores, seg, out);
}

// Round 3
// 646.118 us; speedup vs baseline: 1.1435x; 1.1435x over previous
//
#include <hip/hip_runtime.h>
#include <math.h>

#define NROWS 131072
#define NSEG  64
#define HH    512

typedef unsigned short u16;
typedef unsigned int   u32;
typedef __attribute__((ext_vector_type(8))) short short8;
typedef __attribute__((ext_vector_type(8))) u16   us8;
typedef __attribute__((ext_vector_type(4))) float f32x4;
typedef __attribute__((ext_vector_type(4))) u32   u32x4;

__device__ __forceinline__ u32 f2u(float f){ union {float f; u32 u;} c; c.f=f; return c.u; }
__device__ __forceinline__ float u2f(u32 u){ union {u32 u; float f;} c; c.u=u; return c.f; }
__device__ __forceinline__ u16 bf16_rne(float f){
  u32 u = f2u(f);
  u32 r = u + 0x7FFFu + ((u >> 16) & 1u);
  return (u16)(r >> 16);
}
__device__ __forceinline__ float fast_tanh(float x){
  float e = __expf(2.0f * x);
  return 1.0f - __fdividef(2.0f, e + 1.0f);
}
// async 16B global->LDS; LDS dest is wave-uniform base + lane*16
__device__ __forceinline__ void gload_lds16(const void* g, void* l) {
  __builtin_amdgcn_global_load_lds((const __attribute__((address_space(1))) void*)g,
                                   (__attribute__((address_space(3))) void*)l, 16, 0, 0);
}

// ---------------- hproj[b][j] = sum_k hidden[b][k] * W[j][k]  (coalesced, reg-resident hidden)
__global__ __launch_bounds__(256)
void hproj_kernel(const float* __restrict__ hidden, const float* __restrict__ W,
                  float* __restrict__ hproj)
{
  const int b    = blockIdx.x;
  const int tid  = threadIdx.x;
  const int wave = tid >> 6;
  const int lane = tid & 63;
  const float* hrow = hidden + (size_t)b * HH + lane * 8;
  const float4 h0 = *(const float4*)(hrow);
  const float4 h1 = *(const float4*)(hrow + 4);
  for (int j = wave; j < HH; j += 4) {
    const float* wrow = W + (size_t)j * 1024 + lane * 8;
    const float4 w0 = *(const float4*)(wrow);
    const float4 w1 = *(const float4*)(wrow + 4);
    float acc = h0.x*w0.x + h0.y*w0.y + h0.z*w0.z + h0.w*w0.w
              + h1.x*w1.x + h1.y*w1.y + h1.z*w1.z + h1.w*w1.w;
    #pragma unroll
    for (int o = 32; o; o >>= 1) acc += __shfl_xor(acc, o);
    if (lane == 0) hproj[(size_t)b * HH + j] = acc;
  }
}

// ---------------- split W2 = W[:, 512:1024] into bf16 hi/lo, row-major [j][k]
__global__ __launch_bounds__(256)
void w2split_kernel(const float* __restrict__ W, u16* __restrict__ hi, u16* __restrict__ lo)
{
  const int idx = blockIdx.x * 256 + threadIdx.x;   // j*512 + k
  const int j = idx >> 9, k = idx & 511;
  const float x = W[(size_t)j * 1024 + 512 + k];
  const u32 u = f2u(x);
  hi[idx] = (u16)(u >> 16);
  lo[idx] = bf16_rne(x - u2f(u & 0xFFFF0000u));
}

// ---------------- fused GEMM: A staged fp32 via global_load_lds (XOR-swizzled),
// ---------------- split hi/lo in registers during compute phase (overlaps MFMA)
__global__ __launch_bounds__(256, 3)
void gemm_fused_kernel(const float* __restrict__ enc,
                       const u16* __restrict__ w2hi, const u16* __restrict__ w2lo,
                       const float* __restrict__ hproj, const float* __restrict__ vvec,
                       const int* __restrict__ seg, float* __restrict__ scores)
{
  __shared__ float sAf[128 * 32];   // 16 KB, fp32 A tile, k-chunk XOR-swizzled
  __shared__ u16   sBh[128 * 32];   // 8 KB
  __shared__ u16   sBl[128 * 32];   // 8 KB

  const int tid  = threadIdx.x;
  const int bx   = blockIdx.x;
  const int row0 = (bx >> 2) * 128;   // col-tile fastest: A re-reads land in L3
  const int col0 = (bx & 3) * 128;

  const int wave = tid >> 6;
  const int lane = tid & 63;
  const int wr   = (wave >> 1) * 64;
  const int wc   = (wave & 1) * 64;
  const int l15  = lane & 15;
  const int quad = lane >> 4;

  // A staging: issue covers 32 rows x 32 floats (4 KB). thread t -> LDS phys chunk t%8
  // of local row t/8; fetch logical chunk (t%8)^(row&6) so reads can unswizzle.
  const int arow = tid >> 3;                              // 0..31
  const int acol = ((tid & 7) ^ (arow & 6)) * 4;          // swizzled fp32 col
  const float* gA = enc + (size_t)(row0 + arow) * HH + acol;
  const int awb = (tid >> 6) * 256;                       // wave-uniform fp32 offset in issue

  // B staging: issue covers 64 rows x 32 u16 (4 KB). phys chunk t%4 of row t/4;
  // fetch logical chunk (t%4)^((row>>1)&3).
  const int brow = tid >> 2;                              // 0..63
  const int bcol = ((tid & 3) ^ ((brow >> 1) & 3)) * 8;   // swizzled u16 col
  const u16* gBh = w2hi + (size_t)(col0 + brow) * HH + bcol;
  const u16* gBl = w2lo + (size_t)(col0 + brow) * HH + bcol;
  const int bwb = (tid >> 6) * 512;                       // wave-uniform u16 offset in issue

  f32x4 acc[4][4];
  #pragma unroll
  for (int i = 0; i < 4; i++)
    #pragma unroll
    for (int j = 0; j < 4; j++)
      acc[i][j] = (f32x4){0.f, 0.f, 0.f, 0.f};

  for (int ks = 0; ks < HH; ks += 32) {
    #pragma unroll
    for (int i = 0; i < 4; i++)
      gload_lds16(gA + (size_t)i * 32 * HH + ks, &sAf[i * 1024 + awb]);
    gload_lds16(gBh + ks,                      &sBh[bwb]);
    gload_lds16(gBh + (size_t)64 * HH + ks,    &sBh[2048 + bwb]);
    gload_lds16(gBl + ks,                      &sBl[bwb]);
    gload_lds16(gBl + (size_t)64 * HH + ks,    &sBl[2048 + bwb]);
    __syncthreads();

    // B fragments: phys chunk-pair = quad ^ ((r>>1)&3)  -> 2-way (free)
    short8 bhf[4], blf[4];
    #pragma unroll
    for (int j = 0; j < 4; j++) {
      const int r  = wc + j * 16 + l15;
      const int off = r * 32 + 8 * (quad ^ ((r >> 1) & 3));
      bhf[j] = *(const short8*)&sBh[off];
      blf[j] = *(const short8*)&sBl[off];
    }

    #pragma unroll
    for (int i = 0; i < 4; i++) {
      const int r  = wr + i * 16 + l15;
      const int ab = r * 32 + 8 * (quad ^ ((r >> 1) & 3));   // 4-way (1.58x)
      const f32x4 x0 = *(const f32x4*)&sAf[ab];
      const f32x4 x1 = *(const f32x4*)&sAf[ab + 4];
      // in-register split: hi = trunc-top16, lo = trunc-top16(exact residual)
      union { u32x4 w; short8 s; } ah, al;
      #pragma unroll
      for (int p = 0; p < 4; p++) {
        const float xa = (p < 2) ? x0[2 * p] : x1[2 * p - 4];
        const float xb = (p < 2) ? x0[2 * p + 1] : x1[2 * p - 3];
        const u32 ua = f2u(xa), ub = f2u(xb);
        ah.w[p] = (ua >> 16) | (ub & 0xFFFF0000u);
        const float ra = xa - u2f(ua & 0xFFFF0000u);
        const float rb = xb - u2f(ub & 0xFFFF0000u);
        al.w[p] = (f2u(ra) >> 16) | (f2u(rb) & 0xFFFF0000u);
      }
      #pragma unroll
      for (int j = 0; j < 4; j++) {
        acc[i][j] = __builtin_amdgcn_mfma_f32_16x16x32_bf16(ah.s, bhf[j], acc[i][j], 0, 0, 0);
        acc[i][j] = __builtin_amdgcn_mfma_f32_16x16x32_bf16(al.s, bhf[j], acc[i][j], 0, 0, 0);
        acc[i][j] = __builtin_amdgcn_mfma_f32_16x16x32_bf16(ah.s, blf[j], acc[i][j], 0, 0, 0);
      }
    }
    __syncthreads();
  }

  // epilogue: + hproj, tanh, dot v, reduce over col-lanes, one atomic per row
  int   jn[4];
  float vv[4];
  #pragma unroll
  for (int j = 0; j < 4; j++) { jn[j] = col0 + wc + j * 16 + l15; vv[j] = vvec[jn[j]]; }

  #pragma unroll
  for (int i = 0; i < 4; i++) {
    #pragma unroll
    for (int r = 0; r < 4; r++) {
      const int gn = row0 + wr + i * 16 + quad * 4 + r;    // C/D: row=(lane>>4)*4+reg
      const float* hp = hproj + (size_t)seg[gn] * HH;
      float p = 0.f;
      #pragma unroll
      for (int j = 0; j < 4; j++) {
        const float c = acc[i][j][r] + hp[jn[j]];
        p += fast_tanh(c) * vv[j];
      }
      p += __shfl_xor(p, 1);
      p += __shfl_xor(p, 2);
      p += __shfl_xor(p, 4);
      p += __shfl_xor(p, 8);
      if (l15 == 0) atomicAdd(&scores[gn], p);
    }
  }
}

// ---------------- segment softmax: one block per segment (ids sorted)
__global__ __launch_bounds__(256)
void seg_softmax_kernel(const float* __restrict__ scores, const int* __restrict__ seg,
                        float* __restrict__ out)
{
  const int b    = blockIdx.x;
  const int tid  = threadIdx.x;
  const int wv   = tid >> 6;
  const int lane = tid & 63;
  __shared__ float red[4];

  int lo = 0, hi = NROWS;
  while (lo < hi) { int mid = (lo + hi) >> 1; if (seg[mid] < b) lo = mid + 1; else hi = mid; }
  const int start = lo;
  lo = 0; hi = NROWS;
  while (lo < hi) { int mid = (lo + hi) >> 1; if (seg[mid] < b + 1) lo = mid + 1; else hi = mid; }
  const int end = lo;

  float lm = -3.4e38f;
  for (int i = start + tid; i < end; i += 256) lm = fmaxf(lm, scores[i]);
  #pragma unroll
  for (int o = 32; o; o >>= 1) lm = fmaxf(lm, __shfl_xor(lm, o));
  if (lane == 0) red[wv] = lm;
  __syncthreads();
  const float gm = fmaxf(fmaxf(red[0], red[1]), fmaxf(red[2], red[3]));
  __syncthreads();

  float ls = 0.f;
  for (int i = start + tid; i < end; i += 256) ls += expf(scores[i] - gm);
  #pragma unroll
  for (int o = 32; o; o >>= 1) ls += __shfl_xor(ls, o);
  if (lane == 0) red[wv] = ls;
  __syncthreads();
  const float denom = red[0] + red[1] + red[2] + red[3];
  const float inv = 1.0f / denom;

  for (int i = start + tid; i < end; i += 256) out[i] = expf(scores[i] - gm) * inv;
}

extern "C" void kernel_launch(void* const* d_in, const int* in_sizes, int n_in,
                              void* d_out, int out_size, void* d_ws, size_t ws_size,
                              hipStream_t stream)
{
  const float* hidden = (const float*)d_in[0];
  const float* enc    = (const float*)d_in[1];
  const int*   seg    = (const int*)d_in[2];
  const float* W      = (const float*)d_in[3];
  const float* vvec   = (const float*)d_in[4];
  float* out = (float*)d_out;

  // ws layout: scores(512KB) | hproj(128KB) | w2hi(512KB) | w2lo(512KB)  ~1.7MB
  float* scores = (float*)d_ws;
  float* hproj  = scores + NROWS;
  u16*   w2hi   = (u16*)(hproj + NSEG * HH);
  u16*   w2lo   = w2hi + (size_t)HH * HH;

  hipMemsetAsync(scores, 0, NROWS * sizeof(float), stream);
  hproj_kernel<<<NSEG, 256, 0, stream>>>(hidden, W, hproj);
  w2split_kernel<<<(HH * HH) / 256, 256, 0, stream>>>(W, w2hi, w2lo);
  gemm_fused_kernel<<<(NROWS / 128) * 4, 256, 0, stream>>>(enc, w2hi, w2lo,
                                                           hproj, vvec, seg, scores);
  seg_softmax_kernel<<<NSEG, 256, 0, stream>>>(scores, seg, out);
}

// Round 4
// 543.109 us; speedup vs baseline: 1.3604x; 1.1897x over previous
//
#include <hip/hip_runtime.h>
#include <math.h>

#define NROWS 131072
#define NSEG  64
#define HH    512

typedef unsigned short u16;
typedef unsigned int   u32;
typedef __attribute__((ext_vector_type(8))) short short8;
typedef __attribute__((ext_vector_type(8))) u16   us8;
typedef __attribute__((ext_vector_type(4))) float f32x4;
typedef __attribute__((ext_vector_type(4))) u32   u32x4;

__device__ __forceinline__ u32 f2u(float f){ union {float f; u32 u;} c; c.f=f; return c.u; }
__device__ __forceinline__ float u2f(u32 u){ union {u32 u; float f;} c; c.u=u; return c.f; }
__device__ __forceinline__ u16 bf16_rne(float f){
  u32 u = f2u(f);
  u32 r = u + 0x7FFFu + ((u >> 16) & 1u);
  return (u16)(r >> 16);
}
__device__ __forceinline__ float fast_tanh(float x){
  float e = __expf(2.0f * x);
  return 1.0f - __fdividef(2.0f, e + 1.0f);
}
// async 16B global->LDS; LDS dest is wave-uniform base + lane*16
__device__ __forceinline__ void gload_lds16(const void* g, void* l) {
  __builtin_amdgcn_global_load_lds((const __attribute__((address_space(1))) void*)g,
                                   (__attribute__((address_space(3))) void*)l, 16, 0, 0);
}

// ---------------- hproj[b][j] = sum_k hidden[b][k] * W[j][k]  (coalesced; 256 blocks)
__global__ __launch_bounds__(256)
void hproj_kernel(const float* __restrict__ hidden, const float* __restrict__ W,
                  float* __restrict__ hproj)
{
  const int b    = blockIdx.x >> 2;          // segment
  const int q    = blockIdx.x & 3;           // j-quarter
  const int tid  = threadIdx.x;
  const int wave = tid >> 6;
  const int lane = tid & 63;
  const float* hrow = hidden + (size_t)b * HH + lane * 8;
  const float4 h0 = *(const float4*)(hrow);
  const float4 h1 = *(const float4*)(hrow + 4);
  for (int j = q * 128 + wave; j < q * 128 + 128; j += 4) {
    const float* wrow = W + (size_t)j * 1024 + lane * 8;
    const float4 w0 = *(const float4*)(wrow);
    const float4 w1 = *(const float4*)(wrow + 4);
    float acc = h0.x*w0.x + h0.y*w0.y + h0.z*w0.z + h0.w*w0.w
              + h1.x*w1.x + h1.y*w1.y + h1.z*w1.z + h1.w*w1.w;
    #pragma unroll
    for (int o = 32; o; o >>= 1) acc += __shfl_xor(acc, o);
    if (lane == 0) hproj[(size_t)b * HH + j] = acc;
  }
}

// ---------------- split W2 = W[:, 512:1024] into bf16 hi/lo, row-major [j][k]
__global__ __launch_bounds__(256)
void w2split_kernel(const float* __restrict__ W, u16* __restrict__ hi, u16* __restrict__ lo)
{
  const int idx = blockIdx.x * 256 + threadIdx.x;   // j*512 + k
  const int j = idx >> 9, k = idx & 511;
  const float x = W[(size_t)j * 1024 + 512 + k];
  const u32 u = f2u(x);
  hi[idx] = (u16)(u >> 16);
  lo[idx] = bf16_rne(x - u2f(u & 0xFFFF0000u));
}

// ---------------- fused GEMM: 128x256 block tile, 2x2 waves of 64x128,
// A staged fp32 via global_load_lds (XOR-swizzled), split hi/lo in-register (v_perm),
// B pre-split bf16 hi/lo. 3-product split-bf16 MFMA, fused tanh+dot-v epilogue.
__global__ __launch_bounds__(256, 2)
void gemm_fused_kernel(const float* __restrict__ enc,
                       const u16* __restrict__ w2hi, const u16* __restrict__ w2lo,
                       const float* __restrict__ hproj, const float* __restrict__ vvec,
                       const int* __restrict__ seg, float* __restrict__ scores)
{
  __shared__ float sAf[128 * 32];   // 16 KB fp32 A tile
  __shared__ u16   sBh[256 * 32];   // 16 KB
  __shared__ u16   sBl[256 * 32];   // 16 KB

  const int tid  = threadIdx.x;
  const int bx   = blockIdx.x;
  const int row0 = (bx >> 1) * 128;   // col-tile fastest: A re-read by the pair hits L2/L3
  const int col0 = (bx & 1) * 256;

  const int wave = tid >> 6;
  const int lane = tid & 63;
  const int wrow = (wave >> 1) * 64;   // wave-tile: 64 rows x 128 cols
  const int wcol = (wave & 1) * 128;
  const int l15  = lane & 15;
  const int quad = lane >> 4;

  // A staging: per issue 32 rows x 32 f32. thread t -> phys chunk t%8 of row t/8;
  // source col swizzled so reads unswizzle: logical chunk (t%8)^(row&6).
  const int arow = tid >> 3;
  const int acol = ((tid & 7) ^ (arow & 6)) * 4;
  const float* gA = enc + (size_t)(row0 + arow) * HH + acol;
  const int awb = (tid >> 6) * 256;    // wave-uniform f32 offset within issue

  // B staging: per issue 64 rows x 32 u16. phys chunk t%4 of row t/4;
  // logical chunk (t%4)^((row>>1)&3).
  const int brow = tid >> 2;
  const int bcol = ((tid & 3) ^ ((brow >> 1) & 3)) * 8;
  const u16* gBh = w2hi + (size_t)(col0 + brow) * HH + bcol;
  const u16* gBl = w2lo + (size_t)(col0 + brow) * HH + bcol;
  const int bwb = (tid >> 6) * 512;    // wave-uniform u16 offset within issue

  f32x4 acc[4][8];
  #pragma unroll
  for (int i = 0; i < 4; i++)
    #pragma unroll
    for (int j = 0; j < 8; j++)
      acc[i][j] = (f32x4){0.f, 0.f, 0.f, 0.f};

  for (int ks = 0; ks < HH; ks += 32) {
    #pragma unroll
    for (int i = 0; i < 4; i++)
      gload_lds16(gA + (size_t)i * 32 * HH + ks, &sAf[i * 1024 + awb]);
    #pragma unroll
    for (int i = 0; i < 4; i++)
      gload_lds16(gBh + (size_t)i * 64 * HH + ks, &sBh[i * 2048 + bwb]);
    #pragma unroll
    for (int i = 0; i < 4; i++)
      gload_lds16(gBl + (size_t)i * 64 * HH + ks, &sBl[i * 2048 + bwb]);
    __syncthreads();

    // ---- A fragments: read fp32, split hi/lo via v_perm (3 VALU/elem) ----
    short8 ah[4], al[4];
    #pragma unroll
    for (int i = 0; i < 4; i++) {
      const int r  = wrow + i * 16 + l15;
      const int ab = r * 32 + (((2 * quad) ^ (r & 6))) * 4;
      const f32x4 x0 = *(const f32x4*)&sAf[ab];
      const f32x4 x1 = *(const f32x4*)&sAf[ab + 4];
      union { u32x4 w; short8 s; } H, L;
      #pragma unroll
      for (int p = 0; p < 4; p++) {
        const float xa = (p < 2) ? x0[2 * p] : x1[2 * p - 4];
        const float xb = (p < 2) ? x0[2 * p + 1] : x1[2 * p - 3];
        const u32 ua = f2u(xa), ub = f2u(xb);
        H.w[p] = __builtin_amdgcn_perm(ub, ua, 0x07060302u);   // [ub_hi16 | ua_hi16]
        const float ra = xa - u2f(ua & 0xFFFF0000u);
        const float rb = xb - u2f(ub & 0xFFFF0000u);
        L.w[p] = __builtin_amdgcn_perm(f2u(rb), f2u(ra), 0x07060302u);
      }
      ah[i] = H.s;
      al[i] = L.s;
    }

    // ---- B streamed per col-frag; 12 MFMA per B pair ----
    #pragma unroll
    for (int j = 0; j < 8; j++) {
      const int rr  = wcol + j * 16 + l15;
      const int off = rr * 32 + (quad ^ ((rr >> 1) & 3)) * 8;
      const short8 bh = *(const short8*)&sBh[off];
      const short8 bl = *(const short8*)&sBl[off];
      #pragma unroll
      for (int i = 0; i < 4; i++) {
        acc[i][j] = __builtin_amdgcn_mfma_f32_16x16x32_bf16(ah[i], bh, acc[i][j], 0, 0, 0);
        acc[i][j] = __builtin_amdgcn_mfma_f32_16x16x32_bf16(al[i], bh, acc[i][j], 0, 0, 0);
        acc[i][j] = __builtin_amdgcn_mfma_f32_16x16x32_bf16(ah[i], bl, acc[i][j], 0, 0, 0);
      }
    }
    __syncthreads();
  }

  // ---- epilogue: + hproj, tanh, dot v, reduce over col-lanes, one atomic/row ----
  int   jn[8];
  float vv[8];
  #pragma unroll
  for (int j = 0; j < 8; j++) { jn[j] = col0 + wcol + j * 16 + l15; vv[j] = vvec[jn[j]]; }

  #pragma unroll
  for (int i = 0; i < 4; i++) {
    #pragma unroll
    for (int r = 0; r < 4; r++) {
      const int gn = row0 + wrow + i * 16 + quad * 4 + r;    // C/D: row=(lane>>4)*4+reg
      const float* hp = hproj + (size_t)seg[gn] * HH;
      float p = 0.f;
      #pragma unroll
      for (int j = 0; j < 8; j++) {
        const float c = acc[i][j][r] + hp[jn[j]];
        p += fast_tanh(c) * vv[j];
      }
      p += __shfl_xor(p, 1);
      p += __shfl_xor(p, 2);
      p += __shfl_xor(p, 4);
      p += __shfl_xor(p, 8);
      if (l15 == 0) atomicAdd(&scores[gn], p);
    }
  }
}

// ---------------- segment softmax: one block per segment (ids sorted)
__global__ __launch_bounds__(256)
void seg_softmax_kernel(const float* __restrict__ scores, const int* __restrict__ seg,
                        float* __restrict__ out)
{
  const int b    = blockIdx.x;
  const int tid  = threadIdx.x;
  const int wv   = tid >> 6;
  const int lane = tid & 63;
  __shared__ float red[4];

  int lo = 0, hi = NROWS;
  while (lo < hi) { int mid = (lo + hi) >> 1; if (seg[mid] < b) lo = mid + 1; else hi = mid; }
  const int start = lo;
  lo = 0; hi = NROWS;
  while (lo < hi) { int mid = (lo + hi) >> 1; if (seg[mid] < b + 1) lo = mid + 1; else hi = mid; }
  const int end = lo;

  float lm = -3.4e38f;
  for (int i = start + tid; i < end; i += 256) lm = fmaxf(lm, scores[i]);
  #pragma unroll
  for (int o = 32; o; o >>= 1) lm = fmaxf(lm, __shfl_xor(lm, o));
  if (lane == 0) red[wv] = lm;
  __syncthreads();
  const float gm = fmaxf(fmaxf(red[0], red[1]), fmaxf(red[2], red[3]));
  __syncthreads();

  float ls = 0.f;
  for (int i = start + tid; i < end; i += 256) ls += expf(scores[i] - gm);
  #pragma unroll
  for (int o = 32; o; o >>= 1) ls += __shfl_xor(ls, o);
  if (lane == 0) red[wv] = ls;
  __syncthreads();
  const float denom = red[0] + red[1] + red[2] + red[3];
  const float inv = 1.0f / denom;

  for (int i = start + tid; i < end; i += 256) out[i] = expf(scores[i] - gm) * inv;
}

extern "C" void kernel_launch(void* const* d_in, const int* in_sizes, int n_in,
                              void* d_out, int out_size, void* d_ws, size_t ws_size,
                              hipStream_t stream)
{
  const float* hidden = (const float*)d_in[0];
  const float* enc    = (const float*)d_in[1];
  const int*   seg    = (const int*)d_in[2];
  const float* W      = (const float*)d_in[3];
  const float* vvec   = (const float*)d_in[4];
  float* out = (float*)d_out;

  // ws layout: scores(512KB) | hproj(128KB) | w2hi(512KB) | w2lo(512KB)  ~1.7MB
  float* scores = (float*)d_ws;
  float* hproj  = scores + NROWS;
  u16*   w2hi   = (u16*)(hproj + NSEG * HH);
  u16*   w2lo   = w2hi + (size_t)HH * HH;

  hipMemsetAsync(scores, 0, NROWS * sizeof(float), stream);
  hproj_kernel<<<NSEG * 4, 256, 0, stream>>>(hidden, W, hproj);
  w2split_kernel<<<(HH * HH) / 256, 256, 0, stream>>>(W, w2hi, w2lo);
  gemm_fused_kernel<<<(NROWS / 128) * 2, 256, 0, stream>>>(enc, w2hi, w2lo,
                                                           hproj, vvec, seg, scores);
  seg_softmax_kernel<<<NSEG, 256, 0, stream>>>(scores, seg, out);
}